// Round 1
// 680.763 us; speedup vs baseline: 1.0661x; 1.0661x over previous
//
#include <hip/hip_runtime.h>
#include <math.h>

#define BIGD 1e10f
#define NPTS 20
#define BPB  4   // batch items per block: one per wave

typedef float f4 __attribute__((ext_vector_type(4)));

__global__ __launch_bounds__(256) void spf_kernel(
    const float* __restrict__ points,    // [B,20,3]
    const float* __restrict__ mask,      // [B,20]
    const float* __restrict__ W_rel,     // [3,64]
    const float* __restrict__ b_rel,     // [64]
    const float* __restrict__ W_dist,    // [1,64]
    const float* __restrict__ b_dist,    // [64]
    const float* __restrict__ emb_count, // [50,64]
    const float* __restrict__ W_den,     // [1,64]
    const float* __restrict__ b_den,     // [64]
    float* __restrict__ out,             // [B,20,256]
    int B)
{
    const int w    = threadIdx.x >> 6;   // wave id 0..3 -> batch item
    const int lane = threadIdx.x & 63;
    const int b    = blockIdx.x * BPB + w;
    const bool active = (b < B);

    // Per-wave staging regions; strides are 16B-aligned (240B / 80B rows).
    __shared__ __align__(16) float sP[BPB][NPTS * 3];
    __shared__ __align__(16) float sM[BPB][NPTS];
    __shared__ float sDen[BPB][NPTS];
    __shared__ float sCd[BPB][NPTS];

    // Vectorized stage: lanes 0..14 load points (15 x float4 = 60 floats),
    // lanes 15..19 load mask (5 x float4 = 20 floats). One instr per lane.
    if (active) {
        if (lane < 15) {
            ((f4*)sP[w])[lane] = ((const f4*)points)[(size_t)b * 15 + lane];
        } else if (lane < 20) {
            ((f4*)sM[w])[lane - 15] = ((const f4*)mask)[(size_t)b * 5 + (lane - 15)];
        }
    }
    __syncthreads();

    // Every thread redundantly reduces its wave's 20 rows (broadcast LDS reads).
    float sm = 0.f, cx = 0.f, cy = 0.f, cz = 0.f;
#pragma unroll
    for (int i = 0; i < NPTS; ++i) {
        const float m = sM[w][i];
        sm += m;
        cx = fmaf(m, sP[w][i * 3 + 0], cx);
        cy = fmaf(m, sP[w][i * 3 + 1], cy);
        cz = fmaf(m, sP[w][i * 3 + 2], cz);
    }
    const float nvf = fmaxf(sm, 1.0f);   // clip(n_valid, 1)
    cx /= nvf; cy /= nvf; cz /= nvf;
    const int nv  = (int)(sm + 0.5f);    // exact: mask is 0.0/1.0
    const int idx = (int)(nvf + 0.5f);   // emb_count row, 1..20

    // Lanes 0..19 of EACH wave: density (top-3 nearest valid) + cdist for own b.
    if (active && lane < NPTS) {
        const int i = lane;
        const float mi = sM[w][i];
        const float px = sP[w][i * 3 + 0], py = sP[w][i * 3 + 1], pz = sP[w][i * 3 + 2];
        float b0 = BIGD, b1 = BIGD, b2 = BIGD;   // ascending 3 smallest
#pragma unroll
        for (int j = 0; j < NPTS; ++j) {
            const float dx = px - sP[w][j * 3 + 0];
            const float dy = py - sP[w][j * 3 + 1];
            const float dz = pz - sP[w][j * 3 + 2];
            const float d2 = dx * dx + dy * dy + dz * dz;
            float d = sqrtf(fmaxf(d2, 1e-12f));
            const bool valid = (j != i) && (mi > 0.f) && (sM[w][j] > 0.f);
            d = valid ? d : BIGD;
            if (d < b0)      { b2 = b1; b1 = b0; b0 = d; }
            else if (d < b1) { b2 = b1; b1 = d; }
            else if (d < b2) { b2 = d; }
        }
        int k = min(3, nv - 1);
        k = max(k, 1);
        float s = b0;
        if (k > 1) s += b1;
        if (k > 2) s += b2;
        const float dens = s / (float)k;
        sDen[w][i] = ((mi > 0.f) && (nv > 1)) ? dens : 0.f;

        const float rx = px - cx, ry = py - cy, rz = pz - cz;
        sCd[w][i] = sqrtf(rx * rx + ry * ry + rz * rz);
    }
    __syncthreads();

    // Output: lane g owns 4 adjacent columns of its wave's b; 20 stores/thread,
    // each wave-store = 1024B contiguous, nontemporal (stream, never re-read).
    const int g      = lane;
    const int region = g >> 4;    // 0:rel_f 1:dist_f 2:count_f 3:den_f
    const int cq     = g & 15;

    f4 w0 = {0,0,0,0}, w1 = {0,0,0,0}, w2 = {0,0,0,0};
    f4 wd = {0,0,0,0}, bb = {0,0,0,0};
    if (region == 0) {
        w0 = ((const f4*)(W_rel +   0))[cq];
        w1 = ((const f4*)(W_rel +  64))[cq];
        w2 = ((const f4*)(W_rel + 128))[cq];
        bb = ((const f4*)b_rel)[cq];
    } else if (region == 1) {
        wd = ((const f4*)W_dist)[cq];
        bb = ((const f4*)b_dist)[cq];
    } else if (region == 2) {
        bb = ((const f4*)(emb_count + (size_t)idx * 64))[cq];
    } else {
        wd = ((const f4*)W_den)[cq];
        bb = ((const f4*)b_den)[cq];
    }
    const bool use_cd = (region == 1);

    if (active) {
        f4* __restrict__ outv = (f4*)(out + (size_t)b * (NPTS * 256));
#pragma unroll
        for (int n = 0; n < NPTS; ++n) {
            const float rx = sP[w][n * 3 + 0] - cx;
            const float ry = sP[w][n * 3 + 1] - cy;
            const float rz = sP[w][n * 3 + 2] - cz;
            const float sc = use_cd ? sCd[w][n] : sDen[w][n];
            f4 v;
            v.x = fmaf(rx, w0.x, fmaf(ry, w1.x, fmaf(rz, w2.x, fmaf(sc, wd.x, bb.x))));
            v.y = fmaf(rx, w0.y, fmaf(ry, w1.y, fmaf(rz, w2.y, fmaf(sc, wd.y, bb.y))));
            v.z = fmaf(rx, w0.z, fmaf(ry, w1.z, fmaf(rz, w2.z, fmaf(sc, wd.z, bb.z))));
            v.w = fmaf(rx, w0.w, fmaf(ry, w1.w, fmaf(rz, w2.w, fmaf(sc, wd.w, bb.w))));
            __builtin_nontemporal_store(v, &outv[n * 64 + g]);
        }
    }
}

extern "C" void kernel_launch(void* const* d_in, const int* in_sizes, int n_in,
                              void* d_out, int out_size, void* d_ws, size_t ws_size,
                              hipStream_t stream) {
    const float* points    = (const float*)d_in[0];
    const float* mask      = (const float*)d_in[1];
    const float* W_rel     = (const float*)d_in[2];
    const float* b_rel     = (const float*)d_in[3];
    const float* W_dist    = (const float*)d_in[4];
    const float* b_dist    = (const float*)d_in[5];
    const float* emb_count = (const float*)d_in[6];
    const float* W_den     = (const float*)d_in[7];
    const float* b_den     = (const float*)d_in[8];
    float* out             = (float*)d_out;

    const int B    = in_sizes[0] / (NPTS * 3);   // 32768
    const int grid = (B + BPB - 1) / BPB;        // 8192
    spf_kernel<<<grid, 256, 0, stream>>>(points, mask, W_rel, b_rel, W_dist, b_dist,
                                         emb_count, W_den, b_den, out, B);
}